// Round 7
// baseline (460.759 us; speedup 1.0000x reference)
//
#include <hip/hip_runtime.h>

// ---------------------------------------------------------------------------
// TransformerBlock on MI355X (gfx950), bf16 MFMA internal compute.
// B=4 T=2048 C=1024 H=16 D=64 FF=4096. All fp32 I/O; bf16 internally.
//
// R6: QKV + FF1 GEMMs ported to the 256x256 8-phase schedule (T2 swizzle +
// T3/T4 counted-vmcnt phases + T5 setprio + T1 XCD swizzle):
//  - BK=64, 8 waves (2Mx4N), 128KB dbuf LDS, global_load_lds w/ pre-swizzled
//    global source (linear LDS dest), XOR swizzle col^=(row&7)*8 on reads.
//  - raw s_barrier phases; vmcnt(0) only at K-tile boundary (loads for tile
//    t+1 stay in flight across all 8 intra-tile barriers).
// proj / FF2 (N=1024: only 128 tiles at 256-wide) stay on the 128^2 kernel.
// Attention unchanged from R5 (118 us, conflicts 0).
// ---------------------------------------------------------------------------

#define DEVI __device__ __forceinline__

typedef float  f32x4  __attribute__((ext_vector_type(4)));
typedef float  f32x16 __attribute__((ext_vector_type(16)));
typedef __bf16 bf16x8 __attribute__((ext_vector_type(8)));
typedef short  s16x8  __attribute__((ext_vector_type(8)));
typedef unsigned int u32x4 __attribute__((ext_vector_type(4)));
typedef unsigned short u16;

DEVI u16 f2bf(float f) {            // native RNE fp32->bf16
    return __builtin_bit_cast(u16, (__bf16)f);
}

DEVI unsigned pk2(float lo, float hi2) {    // {bf16(lo), bf16(hi2)} dword
    return (unsigned)f2bf(lo) | ((unsigned)f2bf(hi2) << 16);
}

DEVI void gload_lds16(const void* g, void* l) {
    __builtin_amdgcn_global_load_lds(
        (__attribute__((address_space(1))) void*)(g),
        (__attribute__((address_space(3))) void*)(l), 16, 0, 0);
}

DEVI f32x4 mfma16(s16x8 a, s16x8 b, f32x4 c) {
    return __builtin_amdgcn_mfma_f32_16x16x32_bf16(
        __builtin_bit_cast(bf16x8, a), __builtin_bit_cast(bf16x8, b), c, 0, 0, 0);
}

DEVI f32x16 mfma32(s16x8 a, s16x8 b, f32x16 c) {
    return __builtin_amdgcn_mfma_f32_32x32x16_bf16(
        __builtin_bit_cast(bf16x8, a), __builtin_bit_cast(bf16x8, b), c, 0, 0, 0);
}

// ---------------------------------------------------------------------------
// Tiled transpose + fp32->bf16: dst[n][k] = src[k][n].  64x64 tile, 256 thr.
// ---------------------------------------------------------------------------
__global__ __launch_bounds__(256) void transpose_cvt(
    const float* __restrict__ src, u16* __restrict__ dst,
    int K, int N, long srcStride, long dstStride)
{
    __shared__ float t[64][65];
    src += (long)blockIdx.z * srcStride;
    dst += (long)blockIdx.z * dstStride;
    int k0 = blockIdx.x * 64, n0 = blockIdx.y * 64;
    int tx = threadIdx.x & 63, ty = threadIdx.x >> 6;
#pragma unroll
    for (int i = 0; i < 16; ++i) {
        int r = ty * 16 + i;
        t[r][tx] = src[(long)(k0 + r) * N + n0 + tx];
    }
    __syncthreads();
#pragma unroll
    for (int i = 0; i < 16; ++i) {
        int r = ty * 16 + i;
        dst[(long)(n0 + r) * K + k0 + tx] = f2bf(t[tx][r]);
    }
}

// ---------------------------------------------------------------------------
// LayerNorm row (C=1024) -> bf16.  1 row / block, 256 threads, float4 loads.
// ---------------------------------------------------------------------------
__global__ __launch_bounds__(256) void ln_bf16(
    const float* __restrict__ x, const float* __restrict__ g,
    const float* __restrict__ b, u16* __restrict__ out)
{
    int row = blockIdx.x, tid = threadIdx.x;
    const float4 v = ((const float4*)(x + (long)row * 1024))[tid];
    float s = v.x + v.y + v.z + v.w;
    float q = v.x * v.x + v.y * v.y + v.z * v.z + v.w * v.w;
#pragma unroll
    for (int m = 1; m < 64; m <<= 1) { s += __shfl_xor(s, m); q += __shfl_xor(q, m); }
    __shared__ float red[8];
    int lane = tid & 63, w = tid >> 6;
    if (lane == 0) { red[w] = s; red[w + 4] = q; }
    __syncthreads();
    s = red[0] + red[1] + red[2] + red[3];
    q = red[4] + red[5] + red[6] + red[7];
    float mu  = s * (1.0f / 1024.0f);
    float var = q * (1.0f / 1024.0f) - mu * mu;
    float rs  = rsqrtf(var + 1e-5f);
    float4 gv = ((const float4*)g)[tid];
    float4 bv = ((const float4*)b)[tid];
    ushort4 o;
    o.x = f2bf((v.x - mu) * rs * gv.x + bv.x);
    o.y = f2bf((v.y - mu) * rs * gv.y + bv.y);
    o.z = f2bf((v.z - mu) * rs * gv.z + bv.z);
    o.w = f2bf((v.w - mu) * rs * gv.w + bv.w);
    ((ushort4*)(out + (long)row * 1024))[tid] = o;
}

// ---------------------------------------------------------------------------
// 256x256 8-phase GEMM.  C = A[M,K] * Bt[N,K]^T, both bf16 K-contiguous.
// 512 thr (8 waves 2Mx4N), BK=64, dbuf 128KB LDS, XOR swizzle (row&7)*8.
// EPI: 0 = QKV scatter (V transposed), 2 = relu(+bias) -> bf16.
// ---------------------------------------------------------------------------
template <int EPI>
__global__ __launch_bounds__(512, 2) void gemm256(
    const u16* __restrict__ A, const u16* __restrict__ Bt,
    int M, int N, int K,
    u16* __restrict__ outB, const float* __restrict__ bias,
    u16* __restrict__ qd, u16* __restrict__ kd, u16* __restrict__ vd)
{
    __shared__ alignas(16) u16 lds[2][2][16384];   // [buf][A/B][256*64]
    int tid = threadIdx.x, lane = tid & 63, w = tid >> 6;
    int l15 = lane & 15, l4 = lane >> 4;
    int wm = w >> 2, wn = w & 3;

    // T1: bijective XCD swizzle on linear block id (nwg % 8 == 0)
    int gx = gridDim.x;
    int nwg = gx * gridDim.y;
    int bid = blockIdx.y * gx + blockIdx.x;
    int swz = (bid & 7) * (nwg >> 3) + (bid >> 3);
    int bx = swz % gx, by = swz / gx;
    long m0 = (long)bx * 256, n0 = (long)by * 256;

    // staging: lane covers row (w*8 + lane>>3) + 64*i, global 16B chunk
    // pre-swizzled: c' = (lane&7) ^ (lane>>3 & 7)  [inverse of read swizzle]
    int srow8 = lane >> 3;
    int sc = ((lane & 7) ^ srow8) * 8;
    const u16* Ags = A + (m0 + w * 8 + srow8) * (long)K + sc;
    const u16* Bgs = Bt + (n0 + w * 8 + srow8) * (long)K + sc;
    int ldsw = w * 512;                           // wave-uniform LDS base (u16)

    // read-side swizzled k-offsets (elements): col ^ (row&7)*8, row&7 = l15&7
    int rc0 = (l4 * 8) ^ ((l15 & 7) * 8);
    int rc1 = (32 + l4 * 8) ^ ((l15 & 7) * 8);

    f32x4 acc[8][4] = {};

    // prologue: stage tile 0 -> buf 0
#pragma unroll
    for (int i = 0; i < 4; ++i) {
        gload_lds16(Ags + (long)i * 64 * K, &lds[0][0][i * 4096 + ldsw]);
        gload_lds16(Bgs + (long)i * 64 * K, &lds[0][1][i * 4096 + ldsw]);
    }
    asm volatile("s_waitcnt vmcnt(0)" ::: "memory");
    __builtin_amdgcn_s_barrier();

    int NT = K >> 6;
#pragma unroll 1
    for (int t = 0; t < NT; ++t) {
        int cur = t & 1;
        const u16* As_ = &lds[cur][0][0];
        const u16* Bs_ = &lds[cur][1][0];

        // ---- phase 1: frags (mh0,k0)+(b,k0); stage tile t+1 ----
        s16x8 a0[4], b0[4];
#pragma unroll
        for (int i = 0; i < 4; ++i)
            a0[i] = *(const s16x8*)&As_[(wm * 128 + i * 16 + l15) * 64 + rc0];
#pragma unroll
        for (int n = 0; n < 4; ++n)
            b0[n] = *(const s16x8*)&Bs_[(wn * 64 + n * 16 + l15) * 64 + rc0];
        if (t + 1 < NT) {
            long kt = (long)(t + 1) * 64;
#pragma unroll
            for (int i = 0; i < 4; ++i) {
                gload_lds16(Ags + (long)i * 64 * K + kt, &lds[cur ^ 1][0][i * 4096 + ldsw]);
                gload_lds16(Bgs + (long)i * 64 * K + kt, &lds[cur ^ 1][1][i * 4096 + ldsw]);
            }
        }
        __builtin_amdgcn_s_barrier();
        asm volatile("s_waitcnt lgkmcnt(0)" ::: "memory");
        __builtin_amdgcn_sched_barrier(0);
        __builtin_amdgcn_s_setprio(1);
#pragma unroll
        for (int mi = 0; mi < 4; ++mi)
#pragma unroll
            for (int n = 0; n < 4; ++n)
                acc[mi][n] = mfma16(a0[mi], b0[n], acc[mi][n]);
        __builtin_amdgcn_s_setprio(0);
        __builtin_amdgcn_s_barrier();

        // ---- phase 2: (mh1,k0) ----
        s16x8 a1[4];
#pragma unroll
        for (int i = 0; i < 4; ++i)
            a1[i] = *(const s16x8*)&As_[(wm * 128 + 64 + i * 16 + l15) * 64 + rc0];
        __builtin_amdgcn_s_barrier();
        asm volatile("s_waitcnt lgkmcnt(0)" ::: "memory");
        __builtin_amdgcn_sched_barrier(0);
        __builtin_amdgcn_s_setprio(1);
#pragma unroll
        for (int mi = 0; mi < 4; ++mi)
#pragma unroll
            for (int n = 0; n < 4; ++n)
                acc[4 + mi][n] = mfma16(a1[mi], b0[n], acc[4 + mi][n]);
        __builtin_amdgcn_s_setprio(0);
        __builtin_amdgcn_s_barrier();

        // ---- phase 3: (mh0,k1)+(b,k1) ----
        s16x8 a2[4], b1v[4];
#pragma unroll
        for (int i = 0; i < 4; ++i)
            a2[i] = *(const s16x8*)&As_[(wm * 128 + i * 16 + l15) * 64 + rc1];
#pragma unroll
        for (int n = 0; n < 4; ++n)
            b1v[n] = *(const s16x8*)&Bs_[(wn * 64 + n * 16 + l15) * 64 + rc1];
        __builtin_amdgcn_s_barrier();
        asm volatile("s_waitcnt lgkmcnt(0)" ::: "memory");
        __builtin_amdgcn_sched_barrier(0);
        __builtin_amdgcn_s_setprio(1);
#pragma unroll
        for (int mi = 0; mi < 4; ++mi)
#pragma unroll
            for (int n = 0; n < 4; ++n)
                acc[mi][n] = mfma16(a2[mi], b1v[n], acc[mi][n]);
        __builtin_amdgcn_s_setprio(0);
        __builtin_amdgcn_s_barrier();

        // ---- phase 4: (mh1,k1); tile-boundary vmcnt ----
        s16x8 a3[4];
#pragma unroll
        for (int i = 0; i < 4; ++i)
            a3[i] = *(const s16x8*)&As_[(wm * 128 + 64 + i * 16 + l15) * 64 + rc1];
        __builtin_amdgcn_s_barrier();
        asm volatile("s_waitcnt lgkmcnt(0)" ::: "memory");
        __builtin_amdgcn_sched_barrier(0);
        __builtin_amdgcn_s_setprio(1);
#pragma unroll
        for (int mi = 0; mi < 4; ++mi)
#pragma unroll
            for (int n = 0; n < 4; ++n)
                acc[4 + mi][n] = mfma16(a3[mi], b1v[n], acc[4 + mi][n]);
        __builtin_amdgcn_s_setprio(0);
        asm volatile("s_waitcnt vmcnt(0)" ::: "memory");
        __builtin_amdgcn_s_barrier();
    }

    // ---- epilogue ----
#pragma unroll
    for (int mf = 0; mf < 8; ++mf)
#pragma unroll
        for (int n = 0; n < 4; ++n)
#pragma unroll
            for (int r = 0; r < 4; ++r) {
                long row = m0 + wm * 128 + mf * 16 + l4 * 4 + r;
                long col = n0 + wn * 64 + n * 16 + l15;
                float val = acc[mf][n][r];
                if constexpr (EPI == 0) {
                    int c = (int)col;
                    int which = c >> 10, hh = (c >> 6) & 15, dd = c & 63;
                    int bb = (int)(row >> 11), tt = (int)(row & 2047);
                    if (which == 2) {
                        vd[((long)(bb * 16 + hh) * 64 + dd) * 2048 + tt] = f2bf(val);
                    } else {
                        u16* dst = which == 0 ? qd : kd;
                        dst[((long)(bb * 16 + hh) * 2048 + tt) * 64 + dd] = f2bf(val);
                    }
                } else {
                    float t2 = val + bias[col];
                    outB[row * N + col] = f2bf(t2 > 0.f ? t2 : 0.f);
                }
            }
}

// ---------------------------------------------------------------------------
// GEMM 128x128 (m97 structure) for proj / FF2.
// EPI: 1 = +bias +resid -> fp32
// ---------------------------------------------------------------------------
template <int EPI>
__global__ __launch_bounds__(256, 3) void gemm_bt(
    const u16* __restrict__ A, const u16* __restrict__ Bt,
    int M, int N, int K,
    float* __restrict__ outF, u16* __restrict__ outB,
    const float* __restrict__ bias, const float* __restrict__ resid,
    u16* __restrict__ qd, u16* __restrict__ kd, u16* __restrict__ vd)
{
    __shared__ alignas(16) u16 As[128 * 32];
    __shared__ alignas(16) u16 Bs[128 * 32];
    int tid = threadIdx.x;
    int lane = tid & 63, w = tid >> 6;
    int wm = w & 1, wn = w >> 1;
    int l15 = lane & 15, l4 = lane >> 4;
    long m0 = (long)blockIdx.x * 128, n0 = (long)blockIdx.y * 128;
    const u16* Ag = A + m0 * K;
    const u16* Bg = Bt + n0 * K;
    int scol = (lane & 3) * 8;
    int srow0 = (w * 2 + 0) * 16 + (lane >> 2);
    int srow1 = (w * 2 + 1) * 16 + (lane >> 2);

    f32x4 acc[4][4] = {};

    for (int kt = 0; kt < K; kt += 32) {
        gload_lds16(Ag + (long)srow0 * K + kt + scol, &As[(w * 2 + 0) * 512]);
        gload_lds16(Ag + (long)srow1 * K + kt + scol, &As[(w * 2 + 1) * 512]);
        gload_lds16(Bg + (long)srow0 * K + kt + scol, &Bs[(w * 2 + 0) * 512]);
        gload_lds16(Bg + (long)srow1 * K + kt + scol, &Bs[(w * 2 + 1) * 512]);
        __syncthreads();
        s16x8 a[4], b[4];
#pragma unroll
        for (int m = 0; m < 4; ++m)
            a[m] = *(const s16x8*)&As[(wm * 64 + m * 16 + l15) * 32 + l4 * 8];
#pragma unroll
        for (int n = 0; n < 4; ++n)
            b[n] = *(const s16x8*)&Bs[(wn * 64 + n * 16 + l15) * 32 + l4 * 8];
#pragma unroll
        for (int m = 0; m < 4; ++m)
#pragma unroll
            for (int n = 0; n < 4; ++n)
                acc[m][n] = mfma16(a[m], b[n], acc[m][n]);
        __syncthreads();
    }

    long mbase = m0 + wm * 64;
    long nbase = n0 + wn * 64;
#pragma unroll
    for (int m = 0; m < 4; ++m)
#pragma unroll
        for (int n = 0; n < 4; ++n)
#pragma unroll
            for (int r = 0; r < 4; ++r) {
                long row = mbase + m * 16 + l4 * 4 + r;
                long col = nbase + n * 16 + l15;
                float val = acc[m][n][r];
                if constexpr (EPI == 1) {
                    outF[row * N + col] = val + bias[col] + resid[row * N + col];
                }
            }
}

// ---------------------------------------------------------------------------
// Causal flash attention, swapped-operand 32x32 MFMA (unchanged from R5).
// ---------------------------------------------------------------------------
__global__ __launch_bounds__(256, 4) void attn_kernel(
    const u16* __restrict__ Q, const u16* __restrict__ K,
    const u16* __restrict__ Vt, u16* __restrict__ O)
{
    constexpr int PAD = 72;
    constexpr float SC2 = 0.125f * 1.44269504088896f;   // scale * log2(e)
    constexpr float THR = 11.5416f;                     // 8 * log2(e)
    __shared__ alignas(16) u16 Ks[2][64 * PAD];
    __shared__ alignas(16) u16 Vts[2][64 * PAD];
    __shared__ alignas(16) float xbuf[4][32];           // per-wave bounce
    int tid = threadIdx.x, lane = tid & 63, w = tid >> 6;
    int l31 = lane & 31, hi = lane >> 5;
    bool h = (hi != 0);
    int qp = blockIdx.x, hh = blockIdx.y, bb = blockIdx.z;
    const long hbase = ((long)(bb * 16 + hh)) * 2048 * 64;

    int srow[2], scol8[2];
#pragma unroll
    for (int i = 0; i < 2; ++i) {
        int c = tid + 256 * i;
        srow[i] = c >> 3;
        scol8[i] = (c & 7) * 8;
    }

#pragma unroll 1
    for (int ph = 0; ph < 2; ++ph) {
        int qt = ph == 0 ? qp : 15 - qp;
        int q0w = qt * 128 + w * 32;
        int nt = 2 * qt + 2;
        int qv = q0w + l31;                 // this lane's q row

        s16x8 bq[4];
#pragma unroll
        for (int c = 0; c < 4; ++c)
            bq[c] = *(const s16x8*)&Q[hbase + (long)(q0w + l31) * 64 + c * 16 + hi * 8];

        f32x16 o0 = {}, o1 = {};            // O[q=crow][d=l31 | 32+l31]
        float mrow = -1e30f, lrow = 0.f;

        s16x8 kr[2], vr[2];
        {
            const u16* Kg = K + hbase;
            const u16* Vg = Vt + hbase;
#pragma unroll
            for (int i = 0; i < 2; ++i) {
                s16x8 k0 = *(const s16x8*)&Kg[srow[i] * 64 + scol8[i]];
                s16x8 v0 = *(const s16x8*)&Vg[(long)srow[i] * 2048 + scol8[i]];
                *(s16x8*)&Ks[0][srow[i] * PAD + scol8[i]]  = k0;
                *(s16x8*)&Vts[0][srow[i] * PAD + scol8[i]] = v0;
            }
            if (nt > 1) {
                const u16* Kg1 = K + hbase + 64 * 64;
                const u16* Vg1 = Vt + hbase + 64;
#pragma unroll
                for (int i = 0; i < 2; ++i) {
                    kr[i] = *(const s16x8*)&Kg1[srow[i] * 64 + scol8[i]];
                    vr[i] = *(const s16x8*)&Vg1[(long)srow[i] * 2048 + scol8[i]];
                }
            }
        }
        __syncthreads();

#pragma unroll 1
        for (int kt = 0; kt < nt; ++kt) {
            int cur = kt & 1;
            if (kt + 1 < nt) {
#pragma unroll
                for (int i = 0; i < 2; ++i) {
                    *(s16x8*)&Ks[cur ^ 1][srow[i] * PAD + scol8[i]]  = kr[i];
                    *(s16x8*)&Vts[cur ^ 1][srow[i] * PAD + scol8[i]] = vr[i];
                }
            }
            if (kt + 2 < nt) {
                const u16* Kg = K + hbase + (long)(kt + 2) * 64 * 64;
                const u16* Vg = Vt + hbase + (long)(kt + 2) * 64;
#pragma unroll
                for (int i = 0; i < 2; ++i) {
                    kr[i] = *(const s16x8*)&Kg[srow[i] * 64 + scol8[i]];
                    vr[i] = *(const s16x8*)&Vg[(long)srow[i] * 2048 + scol8[i]];
                }
            }

#pragma unroll
            for (int k2 = 0; k2 < 2; ++k2) {
                int kbase = kt * 64 + k2 * 32;
                if (kbase <= q0w + 31) {    // else fully masked for this wave
                    f32x16 s = {};
                    __builtin_amdgcn_s_setprio(1);
#pragma unroll
                    for (int c = 0; c < 4; ++c) {
                        s16x8 ak = *(const s16x8*)&Ks[cur][(k2 * 32 + l31) * PAD + c * 16 + hi * 8];
                        s = mfma32(ak, bq[c], s);
                    }
                    __builtin_amdgcn_s_setprio(0);

                    int khi = kbase + 4 * hi;
                    if (kbase + 31 > q0w) {
#pragma unroll
                        for (int r = 0; r < 16; ++r) {
                            int kg = khi + ((r & 3) + 8 * (r >> 2));
                            float sv = s[r] * SC2;
                            s[r] = (kg > qv) ? -1e30f : sv;
                        }
                    } else {
#pragma unroll
                        for (int r = 0; r < 16; ++r) s[r] *= SC2;
                    }

                    float t8[8], t4[4], t2[2];
#pragma unroll
                    for (int r = 0; r < 8; ++r) t8[r] = fmaxf(s[r], s[r + 8]);
#pragma unroll
                    for (int r = 0; r < 4; ++r) t4[r] = fmaxf(t8[r], t8[r + 4]);
                    t2[0] = fmaxf(t4[0], t4[2]); t2[1] = fmaxf(t4[1], t4[3]);
                    float pm = fmaxf(t2[0], t2[1]);
                    pm = fmaxf(pm, __shfl_xor(pm, 32));

                    int allok = __all(pm - mrow <= THR);
                    float ef = 1.f;
                    if (!allok) {
                        float mn = fmaxf(mrow, pm);
                        ef = exp2f(mrow - mn);
                        mrow = mn;
                    }
                    float a8[8], a4[4];
#pragma unroll
                    for (int r = 0; r < 16; ++r) s[r] = exp2f(s[r] - mrow);
#pragma unroll
                    for (int r = 0; r < 8; ++r) a8[r] = s[r] + s[r + 8];
#pragma unroll
                    for (int r = 0; r < 4; ++r) a4[r] = a8[r] + a8[r + 4];
                    float rsum = (a4[0] + a4[1]) + (a4[2] + a4[3]);
                    rsum += __shfl_xor(rsum, 32);

                    if (!allok) {
                        lrow = lrow * ef + rsum;
                        xbuf[w][l31] = ef;
#pragma unroll
                        for (int rr = 0; rr < 4; ++rr) {
                            f32x4 efv = *(const f32x4*)&xbuf[w][rr * 8 + hi * 4];
#pragma unroll
                            for (int j = 0; j < 4; ++j) {
                                o0[rr * 4 + j] *= efv[j];
                                o1[rr * 4 + j] *= efv[j];
                            }
                        }
                    } else {
                        lrow += rsum;
                    }

                    unsigned c0 = pk2(s[0],  s[1]),  c1 = pk2(s[2],  s[3]);
                    unsigned c2 = pk2(s[4],  s[5]),  c3 = pk2(s[6],  s[7]);
                    unsigned c4 = pk2(s[8],  s[9]),  c5 = pk2(s[10], s[11]);
                    unsigned c6 = pk2(s[12], s[13]), c7 = pk2(s[14], s[15]);
                    unsigned x0 = __shfl_xor((int)c0, 32), x1 = __shfl_xor((int)c1, 32);
                    unsigned x2 = __shfl_xor((int)c2, 32), x3 = __shfl_xor((int)c3, 32);
                    unsigned x4 = __shfl_xor((int)c4, 32), x5 = __shfl_xor((int)c5, 32);
                    unsigned x6 = __shfl_xor((int)c6, 32), x7 = __shfl_xor((int)c7, 32);
                    u32x4 w0 = { h ? x2 : c0, h ? x3 : c1, h ? c2 : x0, h ? c3 : x1 };
                    u32x4 w1 = { h ? x6 : c4, h ? x7 : c5, h ? c6 : x4, h ? c7 : x5 };
                    s16x8 pa0 = __builtin_bit_cast(s16x8, w0);
                    s16x8 pa1 = __builtin_bit_cast(s16x8, w1);

                    __builtin_amdgcn_s_setprio(1);
#pragma unroll
                    for (int ks = 0; ks < 2; ++ks) {
                        s16x8 pa = ks ? pa1 : pa0;
                        s16x8 bv0 = *(const s16x8*)&Vts[cur][(l31) * PAD + k2 * 32 + ks * 16 + hi * 8];
                        s16x8 bv1 = *(const s16x8*)&Vts[cur][(32 + l31) * PAD + k2 * 32 + ks * 16 + hi * 8];
                        o0 = mfma32(pa, bv0, o0);
                        o1 = mfma32(pa, bv1, o1);
                    }
                    __builtin_amdgcn_s_setprio(0);
                }
            }
            __syncthreads();
        }

        float il = 1.0f / lrow;
        xbuf[w][l31] = il;
        f32x4 ilv[4];
#pragma unroll
        for (int rr = 0; rr < 4; ++rr)
            ilv[rr] = *(const f32x4*)&xbuf[w][rr * 8 + hi * 4];
#pragma unroll
        for (int r = 0; r < 16; ++r) {
            int t = q0w + ((r & 3) + 8 * (r >> 2)) + 4 * hi;
            float sc = ilv[r >> 2][r & 3];
            long rbase = ((long)(bb * 2048 + t)) * 1024 + hh * 64;
            O[rbase + l31]      = f2bf(o0[r] * sc);
            O[rbase + 32 + l31] = f2bf(o1[r] * sc);
        }
        __syncthreads();   // protect LDS before next phase's prologue writes
    }
}

// ---------------------------------------------------------------------------
extern "C" void kernel_launch(void* const* d_in, const int* in_sizes, int n_in,
                              void* d_out, int out_size, void* d_ws, size_t ws_size,
                              hipStream_t stream)
{
    const float* x      = (const float*)d_in[0];
    const float* wq     = (const float*)d_in[1];
    const float* wk     = (const float*)d_in[2];
    const float* wv     = (const float*)d_in[3];
    const float* w_proj = (const float*)d_in[4];
    const float* b_proj = (const float*)d_in[5];
    const float* w1     = (const float*)d_in[6];
    const float* b1     = (const float*)d_in[7];
    const float* w2     = (const float*)d_in[8];
    const float* b2     = (const float*)d_in[9];
    const float* ln1_g  = (const float*)d_in[10];
    const float* ln1_b  = (const float*)d_in[11];
    const float* ln2_g  = (const float*)d_in[12];
    const float* ln2_b  = (const float*)d_in[13];

    char* ws = (char*)d_ws;
    u16*   WQKVt = (u16*)(ws + 0);           // 3072x1024 bf16
    u16*   WPt   = (u16*)(ws + 6291456);     // 1024x1024
    u16*   W1t   = (u16*)(ws + 8388608);     // 4096x1024
    u16*   W2t   = (u16*)(ws + 16777216);    // 1024x4096
    u16*   H     = (u16*)(ws + 25165824);    // 8192x1024 (h, then h2)
    u16*   Qb    = (u16*)(ws + 41943040);    // [B,H,T,D]
    u16*   Kb    = (u16*)(ws + 58720256);    // [B,H,T,D]
    u16*   Vb    = (u16*)(ws + 75497472);    // [B,H,D,T]  (transposed)
    u16*   Ob    = (u16*)(ws + 92274688);    // [B,T,C]
    u16*   FF    = (u16*)(ws + 41943040);    // 8192x4096, overlaps Q..O
    float* X1    = (float*)(ws + 109051904); // 8192x1024 fp32
    float* out   = (float*)d_out;

    transpose_cvt<<<dim3(16, 1, 16), 256, 0, stream>>>(wq, WQKVt,           1024, 64, 65536, 65536);
    transpose_cvt<<<dim3(16, 1, 16), 256, 0, stream>>>(wk, WQKVt + 1048576, 1024, 64, 65536, 65536);
    transpose_cvt<<<dim3(16, 1, 16), 256, 0, stream>>>(wv, WQKVt + 2097152, 1024, 64, 65536, 65536);
    transpose_cvt<<<dim3(16, 16, 1), 256, 0, stream>>>(w_proj, WPt, 1024, 1024, 0, 0);
    transpose_cvt<<<dim3(16, 64, 1), 256, 0, stream>>>(w1, W1t, 1024, 4096, 0, 0);
    transpose_cvt<<<dim3(64, 16, 1), 256, 0, stream>>>(w2, W2t, 4096, 1024, 0, 0);

    ln_bf16<<<8192, 256, 0, stream>>>(x, ln1_g, ln1_b, H);

    gemm256<0><<<dim3(32, 12), 512, 0, stream>>>(H, WQKVt, 8192, 3072, 1024,
        nullptr, nullptr, Qb, Kb, Vb);

    attn_kernel<<<dim3(8, 16, 4), 256, 0, stream>>>(Qb, Kb, Vb, Ob);

    gemm_bt<1><<<dim3(64, 8), 256, 0, stream>>>(Ob, WPt, 8192, 1024, 1024,
        X1, nullptr, b_proj, x, nullptr, nullptr, nullptr);

    ln_bf16<<<8192, 256, 0, stream>>>(X1, ln2_g, ln2_b, H);

    gemm256<2><<<dim3(32, 16), 512, 0, stream>>>(H, W1t, 8192, 4096, 1024,
        FF, b1, nullptr, nullptr, nullptr);

    gemm_bt<1><<<dim3(64, 8), 256, 0, stream>>>(FF, W2t, 8192, 1024, 4096,
        out, nullptr, b2, X1, nullptr, nullptr, nullptr);
}

// Round 8
// 453.493 us; speedup vs baseline: 1.0160x; 1.0160x over previous
//
#include <hip/hip_runtime.h>

// ---------------------------------------------------------------------------
// TransformerBlock on MI355X (gfx950), bf16 MFMA internal compute.
// B=4 T=2048 C=1024 H=16 D=64 FF=4096. All fp32 I/O; bf16 internally.
//
// R7: gemm256 v2 — true counted-vmcnt pipeline (T4), fixing R6's drain-0:
//  - BK=32, 4-buffer LDS ring (128KB), prefetch 2 K-tiles ahead
//  - vmcnt(4) at tile boundary (never 0 in loop); lgkmcnt(4)/(0) phases
//  - ONE barrier per K-tile (was 8)
//  - 2-way-free swizzle chunk^=(row>>1)&3, pre-swizzled global source
// ---------------------------------------------------------------------------

#define DEVI __device__ __forceinline__

typedef float  f32x4  __attribute__((ext_vector_type(4)));
typedef float  f32x16 __attribute__((ext_vector_type(16)));
typedef __bf16 bf16x8 __attribute__((ext_vector_type(8)));
typedef short  s16x8  __attribute__((ext_vector_type(8)));
typedef unsigned int u32x4 __attribute__((ext_vector_type(4)));
typedef unsigned short u16;

DEVI u16 f2bf(float f) {            // native RNE fp32->bf16
    return __builtin_bit_cast(u16, (__bf16)f);
}

DEVI unsigned pk2(float lo, float hi2) {    // {bf16(lo), bf16(hi2)} dword
    return (unsigned)f2bf(lo) | ((unsigned)f2bf(hi2) << 16);
}

DEVI void gload_lds16(const void* g, void* l) {
    __builtin_amdgcn_global_load_lds(
        (__attribute__((address_space(1))) void*)(g),
        (__attribute__((address_space(3))) void*)(l), 16, 0, 0);
}

DEVI f32x4 mfma16(s16x8 a, s16x8 b, f32x4 c) {
    return __builtin_amdgcn_mfma_f32_16x16x32_bf16(
        __builtin_bit_cast(bf16x8, a), __builtin_bit_cast(bf16x8, b), c, 0, 0, 0);
}

DEVI f32x16 mfma32(s16x8 a, s16x8 b, f32x16 c) {
    return __builtin_amdgcn_mfma_f32_32x32x16_bf16(
        __builtin_bit_cast(bf16x8, a), __builtin_bit_cast(bf16x8, b), c, 0, 0, 0);
}

// ---------------------------------------------------------------------------
// Tiled transpose + fp32->bf16: dst[n][k] = src[k][n].  64x64 tile, 256 thr.
// ---------------------------------------------------------------------------
__global__ __launch_bounds__(256) void transpose_cvt(
    const float* __restrict__ src, u16* __restrict__ dst,
    int K, int N, long srcStride, long dstStride)
{
    __shared__ float t[64][65];
    src += (long)blockIdx.z * srcStride;
    dst += (long)blockIdx.z * dstStride;
    int k0 = blockIdx.x * 64, n0 = blockIdx.y * 64;
    int tx = threadIdx.x & 63, ty = threadIdx.x >> 6;
#pragma unroll
    for (int i = 0; i < 16; ++i) {
        int r = ty * 16 + i;
        t[r][tx] = src[(long)(k0 + r) * N + n0 + tx];
    }
    __syncthreads();
#pragma unroll
    for (int i = 0; i < 16; ++i) {
        int r = ty * 16 + i;
        dst[(long)(n0 + r) * K + k0 + tx] = f2bf(t[tx][r]);
    }
}

// ---------------------------------------------------------------------------
// LayerNorm row (C=1024) -> bf16.  1 row / block, 256 threads, float4 loads.
// ---------------------------------------------------------------------------
__global__ __launch_bounds__(256) void ln_bf16(
    const float* __restrict__ x, const float* __restrict__ g,
    const float* __restrict__ b, u16* __restrict__ out)
{
    int row = blockIdx.x, tid = threadIdx.x;
    const float4 v = ((const float4*)(x + (long)row * 1024))[tid];
    float s = v.x + v.y + v.z + v.w;
    float q = v.x * v.x + v.y * v.y + v.z * v.z + v.w * v.w;
#pragma unroll
    for (int m = 1; m < 64; m <<= 1) { s += __shfl_xor(s, m); q += __shfl_xor(q, m); }
    __shared__ float red[8];
    int lane = tid & 63, w = tid >> 6;
    if (lane == 0) { red[w] = s; red[w + 4] = q; }
    __syncthreads();
    s = red[0] + red[1] + red[2] + red[3];
    q = red[4] + red[5] + red[6] + red[7];
    float mu  = s * (1.0f / 1024.0f);
    float var = q * (1.0f / 1024.0f) - mu * mu;
    float rs  = rsqrtf(var + 1e-5f);
    float4 gv = ((const float4*)g)[tid];
    float4 bv = ((const float4*)b)[tid];
    ushort4 o;
    o.x = f2bf((v.x - mu) * rs * gv.x + bv.x);
    o.y = f2bf((v.y - mu) * rs * gv.y + bv.y);
    o.z = f2bf((v.z - mu) * rs * gv.z + bv.z);
    o.w = f2bf((v.w - mu) * rs * gv.w + bv.w);
    ((ushort4*)(out + (long)row * 1024))[tid] = o;
}

// ---------------------------------------------------------------------------
// 256x256 GEMM v2.  C = A[M,K] * Bt[N,K]^T, bf16 K-contiguous.
// 512 thr (8 waves 2Mx4N), BK=32, 4-buffer LDS ring, prefetch 2 ahead,
// counted vmcnt(4) at tile boundaries, 1 barrier/tile.
// Swizzle: LDS chunk' = chunk ^ ((row>>1)&3)  (2-way = free).
// EPI: 0 = QKV scatter (V transposed), 2 = relu(+bias) -> bf16.
// ---------------------------------------------------------------------------
template <int EPI>
__global__ __launch_bounds__(512, 2) void gemm256(
    const u16* __restrict__ A, const u16* __restrict__ Bt,
    int M, int N, int K,
    u16* __restrict__ outB, const float* __restrict__ bias,
    u16* __restrict__ qd, u16* __restrict__ kd, u16* __restrict__ vd)
{
    __shared__ alignas(16) u16 lds[4][2][8192];   // [ring buf][A/B][256*32]
    int tid = threadIdx.x, lane = tid & 63, w = tid >> 6;
    int l15 = lane & 15, l4 = lane >> 4;
    int wm = w >> 2, wn = w & 3;

    // T1: bijective XCD swizzle (nwg % 8 == 0)
    int gx = gridDim.x;
    int nwg = gx * gridDim.y;
    int bid = blockIdx.y * gx + blockIdx.x;
    int swz = (bid & 7) * (nwg >> 3) + (bid >> 3);
    int bx = swz % gx, by = swz / gx;
    long m0 = (long)bx * 256, n0 = (long)by * 256;

    // staging: per lane 2x16B per operand per tile; global source
    // pre-swizzled so linear LDS dest yields chunk' = chunk ^ ((row>>1)&3)
    long soff0, soff1; int ldso0, ldso1;
    {
        int cI0 = w * 64 + lane;
        int r0 = cI0 >> 2, p0 = cI0 & 3;
        soff0 = (long)r0 * K + (p0 ^ ((r0 >> 1) & 3)) * 8;
        ldso0 = w * 512;
        int cI1 = 512 + cI0;
        int r1 = cI1 >> 2, p1 = cI1 & 3;
        soff1 = (long)r1 * K + (p1 ^ ((r1 >> 1) & 3)) * 8;
        ldso1 = 4096 + w * 512;
    }
    const u16* Ag = A + m0 * K;
    const u16* Bg = Bt + n0 * K;

#define STAGE(tt) do {                                                  \
        int _b = (tt) & 3;                                              \
        long _kt = (long)(tt) * 32;                                     \
        gload_lds16(Ag + soff0 + _kt, &lds[_b][0][ldso0]);              \
        gload_lds16(Bg + soff0 + _kt, &lds[_b][1][ldso0]);              \
        gload_lds16(Ag + soff1 + _kt, &lds[_b][0][ldso1]);              \
        gload_lds16(Bg + soff1 + _kt, &lds[_b][1][ldso1]);              \
    } while (0)

    // read-side swizzled k-chunk offset (u16): (l4 ^ ((row>>1)&3)) * 8
    int rc = (l4 ^ ((l15 >> 1) & 3)) * 8;

    f32x4 acc[8][4] = {};

    STAGE(0);
    STAGE(1);
    asm volatile("s_waitcnt vmcnt(4)" ::: "memory");   // tile 0 landed
    __builtin_amdgcn_s_barrier();

    int NT = K >> 5;
#pragma unroll 1
    for (int t = 0; t < NT; ++t) {
        int cb = t & 3;
        const u16* As_ = &lds[cb][0][0];
        const u16* Bs_ = &lds[cb][1][0];

        if (t + 2 < NT) STAGE(t + 2);

        // issue all 12 ds_reads; first 8 feed MFMA cluster 1
        s16x8 a[8], b[4];
#pragma unroll
        for (int i = 0; i < 4; ++i)
            a[i] = *(const s16x8*)&As_[(wm * 128 + i * 16 + l15) * 32 + rc];
#pragma unroll
        for (int n = 0; n < 4; ++n)
            b[n] = *(const s16x8*)&Bs_[(wn * 64 + n * 16 + l15) * 32 + rc];
#pragma unroll
        for (int i = 0; i < 4; ++i)
            a[4 + i] = *(const s16x8*)&As_[(wm * 128 + 64 + i * 16 + l15) * 32 + rc];

        asm volatile("s_waitcnt lgkmcnt(4)" ::: "memory");  // a0-3,b0-3 done
        __builtin_amdgcn_sched_barrier(0);
        __builtin_amdgcn_s_setprio(1);
#pragma unroll
        for (int mi = 0; mi < 4; ++mi)
#pragma unroll
            for (int n = 0; n < 4; ++n)
                acc[mi][n] = mfma16(a[mi], b[n], acc[mi][n]);
        __builtin_amdgcn_s_setprio(0);

        asm volatile("s_waitcnt lgkmcnt(0)" ::: "memory");  // a4-7 done
        __builtin_amdgcn_sched_barrier(0);
        __builtin_amdgcn_s_setprio(1);
#pragma unroll
        for (int mi = 0; mi < 4; ++mi)
#pragma unroll
            for (int n = 0; n < 4; ++n)
                acc[4 + mi][n] = mfma16(a[4 + mi], b[n], acc[4 + mi][n]);
        __builtin_amdgcn_s_setprio(0);

        // boundary: require tile t+1 landed; keep t+2's loads in flight
        if (t + 2 < NT)
            asm volatile("s_waitcnt vmcnt(4)" ::: "memory");
        else
            asm volatile("s_waitcnt vmcnt(0)" ::: "memory");
        __builtin_amdgcn_s_barrier();
    }
#undef STAGE

    // ---- epilogue ----
#pragma unroll
    for (int mf = 0; mf < 8; ++mf)
#pragma unroll
        for (int n = 0; n < 4; ++n)
#pragma unroll
            for (int r = 0; r < 4; ++r) {
                long row = m0 + wm * 128 + mf * 16 + l4 * 4 + r;
                long col = n0 + wn * 64 + n * 16 + l15;
                float val = acc[mf][n][r];
                if constexpr (EPI == 0) {
                    int c = (int)col;
                    int which = c >> 10, hh = (c >> 6) & 15, dd = c & 63;
                    int bb = (int)(row >> 11), tt = (int)(row & 2047);
                    if (which == 2) {
                        vd[((long)(bb * 16 + hh) * 64 + dd) * 2048 + tt] = f2bf(val);
                    } else {
                        u16* dst = which == 0 ? qd : kd;
                        dst[((long)(bb * 16 + hh) * 2048 + tt) * 64 + dd] = f2bf(val);
                    }
                } else {
                    float t2 = val + bias[col];
                    outB[row * N + col] = f2bf(t2 > 0.f ? t2 : 0.f);
                }
            }
}

// ---------------------------------------------------------------------------
// GEMM 128x128 (m97 structure) for proj / FF2.
// EPI: 1 = +bias +resid -> fp32
// ---------------------------------------------------------------------------
template <int EPI>
__global__ __launch_bounds__(256, 3) void gemm_bt(
    const u16* __restrict__ A, const u16* __restrict__ Bt,
    int M, int N, int K,
    float* __restrict__ outF, u16* __restrict__ outB,
    const float* __restrict__ bias, const float* __restrict__ resid,
    u16* __restrict__ qd, u16* __restrict__ kd, u16* __restrict__ vd)
{
    __shared__ alignas(16) u16 As[128 * 32];
    __shared__ alignas(16) u16 Bs[128 * 32];
    int tid = threadIdx.x;
    int lane = tid & 63, w = tid >> 6;
    int wm = w & 1, wn = w >> 1;
    int l15 = lane & 15, l4 = lane >> 4;
    long m0 = (long)blockIdx.x * 128, n0 = (long)blockIdx.y * 128;
    const u16* Ag = A + m0 * K;
    const u16* Bg = Bt + n0 * K;
    int scol = (lane & 3) * 8;
    int srow0 = (w * 2 + 0) * 16 + (lane >> 2);
    int srow1 = (w * 2 + 1) * 16 + (lane >> 2);

    f32x4 acc[4][4] = {};

    for (int kt = 0; kt < K; kt += 32) {
        gload_lds16(Ag + (long)srow0 * K + kt + scol, &As[(w * 2 + 0) * 512]);
        gload_lds16(Ag + (long)srow1 * K + kt + scol, &As[(w * 2 + 1) * 512]);
        gload_lds16(Bg + (long)srow0 * K + kt + scol, &Bs[(w * 2 + 0) * 512]);
        gload_lds16(Bg + (long)srow1 * K + kt + scol, &Bs[(w * 2 + 1) * 512]);
        __syncthreads();
        s16x8 a[4], b[4];
#pragma unroll
        for (int m = 0; m < 4; ++m)
            a[m] = *(const s16x8*)&As[(wm * 64 + m * 16 + l15) * 32 + l4 * 8];
#pragma unroll
        for (int n = 0; n < 4; ++n)
            b[n] = *(const s16x8*)&Bs[(wn * 64 + n * 16 + l15) * 32 + l4 * 8];
#pragma unroll
        for (int m = 0; m < 4; ++m)
#pragma unroll
            for (int n = 0; n < 4; ++n)
                acc[m][n] = mfma16(a[m], b[n], acc[m][n]);
        __syncthreads();
    }

    long mbase = m0 + wm * 64;
    long nbase = n0 + wn * 64;
#pragma unroll
    for (int m = 0; m < 4; ++m)
#pragma unroll
        for (int n = 0; n < 4; ++n)
#pragma unroll
            for (int r = 0; r < 4; ++r) {
                long row = mbase + m * 16 + l4 * 4 + r;
                long col = nbase + n * 16 + l15;
                float val = acc[m][n][r];
                if constexpr (EPI == 1) {
                    outF[row * N + col] = val + bias[col] + resid[row * N + col];
                }
            }
}

// ---------------------------------------------------------------------------
// Causal flash attention, swapped-operand 32x32 MFMA (unchanged from R5).
// ---------------------------------------------------------------------------
__global__ __launch_bounds__(256, 4) void attn_kernel(
    const u16* __restrict__ Q, const u16* __restrict__ K,
    const u16* __restrict__ Vt, u16* __restrict__ O)
{
    constexpr int PAD = 72;
    constexpr float SC2 = 0.125f * 1.44269504088896f;   // scale * log2(e)
    constexpr float THR = 11.5416f;                     // 8 * log2(e)
    __shared__ alignas(16) u16 Ks[2][64 * PAD];
    __shared__ alignas(16) u16 Vts[2][64 * PAD];
    __shared__ alignas(16) float xbuf[4][32];           // per-wave bounce
    int tid = threadIdx.x, lane = tid & 63, w = tid >> 6;
    int l31 = lane & 31, hi = lane >> 5;
    bool h = (hi != 0);
    int qp = blockIdx.x, hh = blockIdx.y, bb = blockIdx.z;
    const long hbase = ((long)(bb * 16 + hh)) * 2048 * 64;

    int srow[2], scol8[2];
#pragma unroll
    for (int i = 0; i < 2; ++i) {
        int c = tid + 256 * i;
        srow[i] = c >> 3;
        scol8[i] = (c & 7) * 8;
    }

#pragma unroll 1
    for (int ph = 0; ph < 2; ++ph) {
        int qt = ph == 0 ? qp : 15 - qp;
        int q0w = qt * 128 + w * 32;
        int nt = 2 * qt + 2;
        int qv = q0w + l31;                 // this lane's q row

        s16x8 bq[4];
#pragma unroll
        for (int c = 0; c < 4; ++c)
            bq[c] = *(const s16x8*)&Q[hbase + (long)(q0w + l31) * 64 + c * 16 + hi * 8];

        f32x16 o0 = {}, o1 = {};            // O[q=crow][d=l31 | 32+l31]
        float mrow = -1e30f, lrow = 0.f;

        s16x8 kr[2], vr[2];
        {
            const u16* Kg = K + hbase;
            const u16* Vg = Vt + hbase;
#pragma unroll
            for (int i = 0; i < 2; ++i) {
                s16x8 k0 = *(const s16x8*)&Kg[srow[i] * 64 + scol8[i]];
                s16x8 v0 = *(const s16x8*)&Vg[(long)srow[i] * 2048 + scol8[i]];
                *(s16x8*)&Ks[0][srow[i] * PAD + scol8[i]]  = k0;
                *(s16x8*)&Vts[0][srow[i] * PAD + scol8[i]] = v0;
            }
            if (nt > 1) {
                const u16* Kg1 = K + hbase + 64 * 64;
                const u16* Vg1 = Vt + hbase + 64;
#pragma unroll
                for (int i = 0; i < 2; ++i) {
                    kr[i] = *(const s16x8*)&Kg1[srow[i] * 64 + scol8[i]];
                    vr[i] = *(const s16x8*)&Vg1[(long)srow[i] * 2048 + scol8[i]];
                }
            }
        }
        __syncthreads();

#pragma unroll 1
        for (int kt = 0; kt < nt; ++kt) {
            int cur = kt & 1;
            if (kt + 1 < nt) {
#pragma unroll
                for (int i = 0; i < 2; ++i) {
                    *(s16x8*)&Ks[cur ^ 1][srow[i] * PAD + scol8[i]]  = kr[i];
                    *(s16x8*)&Vts[cur ^ 1][srow[i] * PAD + scol8[i]] = vr[i];
                }
            }
            if (kt + 2 < nt) {
                const u16* Kg = K + hbase + (long)(kt + 2) * 64 * 64;
                const u16* Vg = Vt + hbase + (long)(kt + 2) * 64;
#pragma unroll
                for (int i = 0; i < 2; ++i) {
                    kr[i] = *(const s16x8*)&Kg[srow[i] * 64 + scol8[i]];
                    vr[i] = *(const s16x8*)&Vg[(long)srow[i] * 2048 + scol8[i]];
                }
            }

#pragma unroll
            for (int k2 = 0; k2 < 2; ++k2) {
                int kbase = kt * 64 + k2 * 32;
                if (kbase <= q0w + 31) {    // else fully masked for this wave
                    f32x16 s = {};
                    __builtin_amdgcn_s_setprio(1);
#pragma unroll
                    for (int c = 0; c < 4; ++c) {
                        s16x8 ak = *(const s16x8*)&Ks[cur][(k2 * 32 + l31) * PAD + c * 16 + hi * 8];
                        s = mfma32(ak, bq[c], s);
                    }
                    __builtin_amdgcn_s_setprio(0);

                    int khi = kbase + 4 * hi;
                    if (kbase + 31 > q0w) {
#pragma unroll
                        for (int r = 0; r < 16; ++r) {
                            int kg = khi + ((r & 3) + 8 * (r >> 2));
                            float sv = s[r] * SC2;
                            s[r] = (kg > qv) ? -1e30f : sv;
                        }
                    } else {
#pragma unroll
                        for (int r = 0; r < 16; ++r) s[r] *= SC2;
                    }

                    float t8[8], t4[4], t2[2];
#pragma unroll
                    for (int r = 0; r < 8; ++r) t8[r] = fmaxf(s[r], s[r + 8]);
#pragma unroll
                    for (int r = 0; r < 4; ++r) t4[r] = fmaxf(t8[r], t8[r + 4]);
                    t2[0] = fmaxf(t4[0], t4[2]); t2[1] = fmaxf(t4[1], t4[3]);
                    float pm = fmaxf(t2[0], t2[1]);
                    pm = fmaxf(pm, __shfl_xor(pm, 32));

                    int allok = __all(pm - mrow <= THR);
                    float ef = 1.f;
                    if (!allok) {
                        float mn = fmaxf(mrow, pm);
                        ef = exp2f(mrow - mn);
                        mrow = mn;
                    }
                    float a8[8], a4[4];
#pragma unroll
                    for (int r = 0; r < 16; ++r) s[r] = exp2f(s[r] - mrow);
#pragma unroll
                    for (int r = 0; r < 8; ++r) a8[r] = s[r] + s[r + 8];
#pragma unroll
                    for (int r = 0; r < 4; ++r) a4[r] = a8[r] + a8[r + 4];
                    float rsum = (a4[0] + a4[1]) + (a4[2] + a4[3]);
                    rsum += __shfl_xor(rsum, 32);

                    if (!allok) {
                        lrow = lrow * ef + rsum;
                        xbuf[w][l31] = ef;
#pragma unroll
                        for (int rr = 0; rr < 4; ++rr) {
                            f32x4 efv = *(const f32x4*)&xbuf[w][rr * 8 + hi * 4];
#pragma unroll
                            for (int j = 0; j < 4; ++j) {
                                o0[rr * 4 + j] *= efv[j];
                                o1[rr * 4 + j] *= efv[j];
                            }
                        }
                    } else {
                        lrow += rsum;
                    }

                    unsigned c0 = pk2(s[0],  s[1]),  c1 = pk2(s[2],  s[3]);
                    unsigned c2 = pk2(s[4],  s[5]),  c3 = pk2(s[6],  s[7]);
                    unsigned c4 = pk2(s[8],  s[9]),  c5 = pk2(s[10], s[11]);
                    unsigned c6 = pk2(s[12], s[13]), c7 = pk2(s[14], s[15]);
                    unsigned x0 = __shfl_xor((int)c0, 32), x1 = __shfl_xor((int)c1, 32);
                    unsigned x2 = __shfl_xor((int)c2, 32), x3 = __shfl_xor((int)c3, 32);
                    unsigned x4 = __shfl_xor((int)c4, 32), x5 = __shfl_xor((int)c5, 32);
                    unsigned x6 = __shfl_xor((int)c6, 32), x7 = __shfl_xor((int)c7, 32);
                    u32x4 w0 = { h ? x2 : c0, h ? x3 : c1, h ? c2 : x0, h ? c3 : x1 };
                    u32x4 w1 = { h ? x6 : c4, h ? x7 : c5, h ? c6 : x4, h ? c7 : x5 };
                    s16x8 pa0 = __builtin_bit_cast(s16x8, w0);
                    s16x8 pa1 = __builtin_bit_cast(s16x8, w1);

                    __builtin_amdgcn_s_setprio(1);
#pragma unroll
                    for (int ks = 0; ks < 2; ++ks) {
                        s16x8 pa = ks ? pa1 : pa0;
                        s16x8 bv0 = *(const s16x8*)&Vts[cur][(l31) * PAD + k2 * 32 + ks * 16 + hi * 8];
                        s16x8 bv1 = *(const s16x8*)&Vts[cur][(32 + l31) * PAD + k2 * 32 + ks * 16 + hi * 8];
                        o0 = mfma32(pa, bv0, o0);
                        o1 = mfma32(pa, bv1, o1);
                    }
                    __builtin_amdgcn_s_setprio(0);
                }
            }
            __syncthreads();
        }

        float il = 1.0f / lrow;
        xbuf[w][l31] = il;
        f32x4 ilv[4];
#pragma unroll
        for (int rr = 0; rr < 4; ++rr)
            ilv[rr] = *(const f32x4*)&xbuf[w][rr * 8 + hi * 4];
#pragma unroll
        for (int r = 0; r < 16; ++r) {
            int t = q0w + ((r & 3) + 8 * (r >> 2)) + 4 * hi;
            float sc = ilv[r >> 2][r & 3];
            long rbase = ((long)(bb * 2048 + t)) * 1024 + hh * 64;
            O[rbase + l31]      = f2bf(o0[r] * sc);
            O[rbase + 32 + l31] = f2bf(o1[r] * sc);
        }
        __syncthreads();   // protect LDS before next phase's prologue writes
    }
}

// ---------------------------------------------------------------------------
extern "C" void kernel_launch(void* const* d_in, const int* in_sizes, int n_in,
                              void* d_out, int out_size, void* d_ws, size_t ws_size,
                              hipStream_t stream)
{
    const float* x      = (const float*)d_in[0];
    const float* wq     = (const float*)d_in[1];
    const float* wk     = (const float*)d_in[2];
    const float* wv     = (const float*)d_in[3];
    const float* w_proj = (const float*)d_in[4];
    const float* b_proj = (const float*)d_in[5];
    const float* w1     = (const float*)d_in[6];
    const float* b1     = (const float*)d_in[7];
    const float* w2     = (const float*)d_in[8];
    const float* b2     = (const float*)d_in[9];
    const float* ln1_g  = (const float*)d_in[10];
    const float* ln1_b  = (const float*)d_in[11];
    const float* ln2_g  = (const float*)d_in[12];
    const float* ln2_b  = (const float*)d_in[13];

    char* ws = (char*)d_ws;
    u16*   WQKVt = (u16*)(ws + 0);           // 3072x1024 bf16
    u16*   WPt   = (u16*)(ws + 6291456);     // 1024x1024
    u16*   W1t   = (u16*)(ws + 8388608);     // 4096x1024
    u16*   W2t   = (u16*)(ws + 16777216);    // 1024x4096
    u16*   H     = (u16*)(ws + 25165824);    // 8192x1024 (h, then h2)
    u16*   Qb    = (u16*)(ws + 41943040);    // [B,H,T,D]
    u16*   Kb    = (u16*)(ws + 58720256);    // [B,H,T,D]
    u16*   Vb    = (u16*)(ws + 75497472);    // [B,H,D,T]  (transposed)
    u16*   Ob    = (u16*)(ws + 92274688);    // [B,T,C]
    u16*   FF    = (u16*)(ws + 41943040);    // 8192x4096, overlaps Q..O
    float* X1    = (float*)(ws + 109051904); // 8192x1024 fp32
    float* out   = (float*)d_out;

    transpose_cvt<<<dim3(16, 1, 16), 256, 0, stream>>>(wq, WQKVt,           1024, 64, 65536, 65536);
    transpose_cvt<<<dim3(16, 1, 16), 256, 0, stream>>>(wk, WQKVt + 1048576, 1024, 64, 65536, 65536);
    transpose_cvt<<<dim3(16, 1, 16), 256, 0, stream>>>(wv, WQKVt + 2097152, 1024, 64, 65536, 65536);
    transpose_cvt<<<dim3(16, 16, 1), 256, 0, stream>>>(w_proj, WPt, 1024, 1024, 0, 0);
    transpose_cvt<<<dim3(16, 64, 1), 256, 0, stream>>>(w1, W1t, 1024, 4096, 0, 0);
    transpose_cvt<<<dim3(64, 16, 1), 256, 0, stream>>>(w2, W2t, 4096, 1024, 0, 0);

    ln_bf16<<<8192, 256, 0, stream>>>(x, ln1_g, ln1_b, H);

    gemm256<0><<<dim3(32, 12), 512, 0, stream>>>(H, WQKVt, 8192, 3072, 1024,
        nullptr, nullptr, Qb, Kb, Vb);

    attn_kernel<<<dim3(8, 16, 4), 256, 0, stream>>>(Qb, Kb, Vb, Ob);

    gemm_bt<1><<<dim3(64, 8), 256, 0, stream>>>(Ob, WPt, 8192, 1024, 1024,
        X1, nullptr, b_proj, x, nullptr, nullptr, nullptr);

    ln_bf16<<<8192, 256, 0, stream>>>(X1, ln2_g, ln2_b, H);

    gemm256<2><<<dim3(32, 16), 512, 0, stream>>>(H, W1t, 8192, 4096, 1024,
        FF, b1, nullptr, nullptr, nullptr);

    gemm_bt<1><<<dim3(64, 8), 256, 0, stream>>>(FF, W2t, 8192, 1024, 4096,
        out, nullptr, b2, X1, nullptr, nullptr, nullptr);
}